// Round 1
// baseline (12597.166 us; speedup 1.0000x reference)
//
#include <hip/hip_runtime.h>
#include <hip/hip_cooperative_groups.h>

namespace cg = cooperative_groups;

#define V 32000
#define E 256
#define D 512
#define B 32
#define T 128
#define SS 128
#define PAD 3
#define BT 4096   // B*T
#define G4 2048   // 4*D

typedef _Float16 f16;
typedef _Float16 f16x8 __attribute__((ext_vector_type(8)));
typedef _Float16 f16x2 __attribute__((ext_vector_type(2)));
typedef float f32x4 __attribute__((ext_vector_type(4)));

// ---------------------------------------------------------------- helpers
__device__ __forceinline__ void gld_lds16(const f16* g, f16* l) {
    __builtin_amdgcn_global_load_lds(
        (__attribute__((address_space(1))) void*)(const_cast<f16*>(g)),
        (__attribute__((address_space(3))) void*)(l),
        16, 0, 0);
}

__device__ __forceinline__ float sigf(float x) { return 1.f / (1.f + __expf(-x)); }

// ---------------------------------------------------------------- prep kernels
__global__ void convertv(const float* __restrict__ src, f16* __restrict__ dst, long n) {
    long i = ((long)blockIdx.x * blockDim.x + threadIdx.x) * 4;
    long stride = (long)gridDim.x * blockDim.x * 4;
    for (; i < n; i += stride) {
        float4 v = *(const float4*)(src + i);
        f16x2 p0; p0[0] = (f16)v.x; p0[1] = (f16)v.y;
        f16x2 p1; p1[0] = (f16)v.z; p1[1] = (f16)v.w;
        *(f16x2*)(dst + i)     = p0;
        *(f16x2*)(dst + i + 2) = p1;
    }
}

__global__ void bias_prep(const float* __restrict__ bih0, const float* __restrict__ bhh0,
                          const float* __restrict__ bih1, const float* __restrict__ bhh1,
                          float* __restrict__ BIH0, float* __restrict__ B1) {
    int i = blockIdx.x * 256 + threadIdx.x;   // 2048 total
    BIH0[i] = bih0[i] + bhh0[i];
    B1[i]   = bih1[i] + bhh1[i];
}

__global__ void embed_kernel(const int* __restrict__ ids, const float* __restrict__ emb,
                             f16* __restrict__ YH) {
    int m = blockIdx.x;      // 0..4095  (= b*T + t, matches tar_ids flat layout)
    int e = threadIdx.x;     // 0..255
    int id = ids[m];
    float v = (id == PAD) ? 0.f : emb[(long)id * E + e];
    YH[(long)m * E + e] = (f16)v;
}

// ---------------------------------------------------------------- MFMA GEMM (A[M,K] row-major, Bm[N,K] row-major, C'[v][n])
// MODE 0: logits -> out[b][v][t] (+bout),  n = b*T+t
// MODE 1: PRE0T[j][n] = C + bias[j]
template<int MODE>
__global__ __launch_bounds__(256) void gemm_bt(const f16* __restrict__ A, const f16* __restrict__ Bm,
                                               const float* __restrict__ bias, float* __restrict__ Cout,
                                               int K) {
    __shared__ f16 As[128 * 32];
    __shared__ f16 Bs[128 * 32];
    int tid  = threadIdx.x;
    int tileM = blockIdx.y * 128, tileN = blockIdx.x * 128;
    int wid = tid >> 6, lane = tid & 63;
    int wy = wid >> 1, wx = wid & 1;

    f32x4 acc[4][4] = {};

    const f16* agp = A  + (long)(tileM + (tid >> 2)) * K + (tid & 3) * 8;
    const f16* bgp = Bm + (long)(tileN + (tid >> 2)) * K + (tid & 3) * 8;
    f16* asl = As + tid * 8;
    f16* bsl = Bs + tid * 8;

    for (int k0 = 0; k0 < K; k0 += 32) {
        gld_lds16(agp + k0,            asl);
        gld_lds16(agp + (long)64 * K + k0, asl + 64 * 32);
        gld_lds16(bgp + k0,            bsl);
        gld_lds16(bgp + (long)64 * K + k0, bsl + 64 * 32);
        __syncthreads();

        int krun = (lane >> 4) * 8;
        f16x8 af[4], bf[4];
#pragma unroll
        for (int mt = 0; mt < 4; mt++)
            af[mt] = *(const f16x8*)&As[(wy * 64 + mt * 16 + (lane & 15)) * 32 + krun];
#pragma unroll
        for (int nt = 0; nt < 4; nt++)
            bf[nt] = *(const f16x8*)&Bs[(wx * 64 + nt * 16 + (lane & 15)) * 32 + krun];
#pragma unroll
        for (int mt = 0; mt < 4; mt++)
#pragma unroll
            for (int nt = 0; nt < 4; nt++)
                acc[mt][nt] = __builtin_amdgcn_mfma_f32_16x16x32_f16(af[mt], bf[nt], acc[mt][nt], 0, 0, 0);
        __syncthreads();
    }

    int col = lane & 15;
#pragma unroll
    for (int mt = 0; mt < 4; mt++) {
        int vrowbase = tileM + wy * 64 + mt * 16 + (lane >> 4) * 4;
#pragma unroll
        for (int nt = 0; nt < 4; nt++) {
            int n = tileN + wx * 64 + nt * 16 + col;
            f32x4 c = acc[mt][nt];
            if (MODE == 0) {
                int b_ = n >> 7, t_ = n & 127;
                long obase = (long)b_ * V * T + t_;
#pragma unroll
                for (int r = 0; r < 4; r++) {
                    int v_ = vrowbase + r;
                    Cout[obase + (long)v_ * T] = c[r] + bias[v_];
                }
            } else {
#pragma unroll
                for (int r = 0; r < 4; r++) {
                    int j = vrowbase + r;
                    Cout[(long)j * BT + n] = c[r] + bias[j];
                }
            }
        }
    }
}

// ---------------------------------------------------------------- recurrence (cooperative)
// 256 blocks x 256 threads. Thread = (b, d, gate). One f16-dot per thread per phase.
__global__ __launch_bounds__(256) void recurrence(
    const f16* __restrict__ WHH0H, const f16* __restrict__ WIH1H, const f16* __restrict__ WHH1H,
    const float* __restrict__ PRE0T, const float* __restrict__ B1,
    const float* __restrict__ s0_in, const float* __restrict__ c0_in,
    float* __restrict__ S1ALL, f16* __restrict__ S0H, f16* __restrict__ S1H,
    float* __restrict__ C0F, float* __restrict__ C1F, f16* __restrict__ XH) {
    cg::grid_group grid = cg::this_grid();
    int tid = threadIdx.x, blk = blockIdx.x;

    // ---- state init (16384 = B*D elements per array)
    int gt = blk * 256 + tid;
    if (gt < 16384) {
        float s0v = s0_in[gt];
        float s1v = s0_in[16384 + gt];
        S0H[gt]   = (f16)s0v;   // buffer 0
        S1H[gt]   = (f16)s1v;   // buffer 0
        S1ALL[gt] = s1v;        // slot 0 (t = -1)
        C0F[gt]   = c0_in[gt];
        C1F[gt]   = c0_in[16384 + gt];
    }
    grid.sync();

    int p = tid >> 2, gate = tid & 3;
    int b_ = p & 31, dloc = p >> 5;          // dloc 0..1
    int xcd = blk & 7, grp = blk >> 3;       // grp 0..31
    int d = xcd * 64 + grp * 2 + dloc;       // 0..511, XCD-partitioned
    int j = gate * 512 + d;                  // gate row (i,f,g,o order)

    __shared__ float sh[256];

    const f16x8* w0  = (const f16x8*)(WHH0H + (long)j * 512);
    const f16x8* w1i = (const f16x8*)(WIH1H + (long)j * 512);
    const f16x8* w1h = (const f16x8*)(WHH1H + (long)j * 512);
    float b1j = B1[j];
    int   sidx = b_ * 512 + d;

    for (int t = 0; t < T; t++) {
        // ---------------- phase 1: layer-0 cell
        float acc = PRE0T[(long)j * BT + b_ * T + t];
        const f16x8* s8 = (const f16x8*)(S0H + (t & 1) * 16384 + b_ * 512);
#pragma unroll 8
        for (int k = 0; k < 64; k++) {
            union { f16x8 v; f16x2 h[4]; } W, X;
            W.v = w0[k]; X.v = s8[k];
            acc = __builtin_amdgcn_fdot2(W.h[0], X.h[0], acc, false);
            acc = __builtin_amdgcn_fdot2(W.h[1], X.h[1], acc, false);
            acc = __builtin_amdgcn_fdot2(W.h[2], X.h[2], acc, false);
            acc = __builtin_amdgcn_fdot2(W.h[3], X.h[3], acc, false);
        }
        sh[tid] = acc;
        __syncthreads();
        if (gate == 0) {
            float ii = sigf(sh[p * 4 + 0]);
            float ff = sigf(sh[p * 4 + 1]);
            float gg = tanhf(sh[p * 4 + 2]);
            float oo = sigf(sh[p * 4 + 3]);
            float cn = ff * C0F[sidx] + ii * gg;
            C0F[sidx] = cn;
            S0H[((t + 1) & 1) * 16384 + sidx] = (f16)(oo * tanhf(cn));
        }
        grid.sync();

        // ---------------- phase 2: layer-1 cell
        float acc2 = b1j;
        const f16x8* x8 = (const f16x8*)(S0H + ((t + 1) & 1) * 16384 + b_ * 512);
        const f16x8* h8 = (const f16x8*)(S1H + (t & 1) * 16384 + b_ * 512);
#pragma unroll 4
        for (int k = 0; k < 64; k++) {
            union { f16x8 v; f16x2 h[4]; } W, X;
            W.v = w1i[k]; X.v = x8[k];
            acc2 = __builtin_amdgcn_fdot2(W.h[0], X.h[0], acc2, false);
            acc2 = __builtin_amdgcn_fdot2(W.h[1], X.h[1], acc2, false);
            acc2 = __builtin_amdgcn_fdot2(W.h[2], X.h[2], acc2, false);
            acc2 = __builtin_amdgcn_fdot2(W.h[3], X.h[3], acc2, false);
            W.v = w1h[k]; X.v = h8[k];
            acc2 = __builtin_amdgcn_fdot2(W.h[0], X.h[0], acc2, false);
            acc2 = __builtin_amdgcn_fdot2(W.h[1], X.h[1], acc2, false);
            acc2 = __builtin_amdgcn_fdot2(W.h[2], X.h[2], acc2, false);
            acc2 = __builtin_amdgcn_fdot2(W.h[3], X.h[3], acc2, false);
        }
        sh[tid] = acc2;
        __syncthreads();
        if (gate == 0) {
            float ii = sigf(sh[p * 4 + 0]);
            float ff = sigf(sh[p * 4 + 1]);
            float gg = tanhf(sh[p * 4 + 2]);
            float oo = sigf(sh[p * 4 + 3]);
            float cn = ff * C1F[sidx] + ii * gg;
            C1F[sidx] = cn;
            float sn = oo * tanhf(cn);
            S1H[((t + 1) & 1) * 16384 + sidx] = (f16)sn;
            S1ALL[(long)(t + 1) * 16384 + sidx] = sn;
            XH[(long)(b_ * T + t) * 1024 + d] = (f16)sn;
        }
        grid.sync();
    }
}

// ---------------------------------------------------------------- batched attention
// grid (16, 32): blockIdx.y = b, blockIdx.x = chunk of 8 t's. 256 threads.
__global__ __launch_bounds__(256) void attention(const float* __restrict__ h,
                                                 const float* __restrict__ S1ALL,
                                                 f16* __restrict__ XH) {
    int b_ = blockIdx.y, t0 = blockIdx.x * 8;
    int tid = threadIdx.x;
    __shared__ float s1l[8][512];
    __shared__ float sc[8][SS];

    for (int q = 0; q < 16; q++) {
        int idx = q * 256 + tid;         // tt*512 + dd
        int tt = idx >> 9, dd = idx & 511;
        s1l[tt][dd] = S1ALL[(long)(t0 + tt + 1) * 16384 + b_ * 512 + dd];
    }
    __syncthreads();

    int tq = tid >> 5, kq = tid & 31;    // tq: t 0..7, kq: k-seg of 16 floats
    const float* hb = h + (long)b_ * SS * D;

    // registers: this thread's 16 s1 values (reused over all s)
    float s1r[16];
#pragma unroll
    for (int u = 0; u < 16; u++) s1r[u] = s1l[tq][kq * 16 + u];

    for (int s_ = 0; s_ < SS; s_++) {
        const float4* hr = (const float4*)(hb + s_ * D) + kq * 4;
        float partial = 0.f;
#pragma unroll
        for (int u = 0; u < 4; u++) {
            float4 hv = hr[u];
            partial += hv.x * s1r[u * 4 + 0] + hv.y * s1r[u * 4 + 1]
                     + hv.z * s1r[u * 4 + 2] + hv.w * s1r[u * 4 + 3];
        }
        for (int off = 16; off; off >>= 1) partial += __shfl_down(partial, off, 32);
        if (kq == 0) sc[tq][s_] = partial;
    }
    __syncthreads();

    // softmax over s (32 threads per t, 4 scores each)
    {
        float m_ = -1e30f;
#pragma unroll
        for (int u = 0; u < 4; u++) m_ = fmaxf(m_, sc[tq][kq * 4 + u]);
        for (int off = 16; off; off >>= 1) m_ = fmaxf(m_, __shfl_down(m_, off, 32));
        m_ = __shfl(m_, 0, 32);
        float ex[4], sum = 0.f;
#pragma unroll
        for (int u = 0; u < 4; u++) { ex[u] = __expf(sc[tq][kq * 4 + u] - m_); sum += ex[u]; }
        for (int off = 16; off; off >>= 1) sum += __shfl_down(sum, off, 32);
        sum = __shfl(sum, 0, 32);
        float inv = 1.f / sum;
        __syncthreads();
#pragma unroll
        for (int u = 0; u < 4; u++) sc[tq][kq * 4 + u] = ex[u] * inv;
    }
    __syncthreads();

    // z[t][d] = sum_s a[t][s] * h[b][s][d];  thread handles d = tid and tid+256
    float za[8], zb[8];
#pragma unroll
    for (int tt = 0; tt < 8; tt++) { za[tt] = 0.f; zb[tt] = 0.f; }
    for (int s_ = 0; s_ < SS; s_++) {
        float h1 = hb[s_ * D + tid];
        float h2 = hb[s_ * D + 256 + tid];
#pragma unroll
        for (int tt = 0; tt < 8; tt++) {
            float a = sc[tt][s_];
            za[tt] += a * h1;
            zb[tt] += a * h2;
        }
    }
#pragma unroll
    for (int tt = 0; tt < 8; tt++) {
        long m = (long)b_ * T + t0 + tt;
        XH[m * 1024 + 512 + tid] = (f16)za[tt];
        XH[m * 1024 + 768 + tid] = (f16)zb[tt];
    }
}

// ---------------------------------------------------------------- launch
extern "C" void kernel_launch(void* const* d_in, const int* in_sizes, int n_in,
                              void* d_out, int out_size, void* d_ws, size_t ws_size,
                              hipStream_t stream) {
    const int*   tar  = (const int*)d_in[0];
    const float* h    = (const float*)d_in[1];
    const float* s0   = (const float*)d_in[2];
    const float* c0   = (const float*)d_in[3];
    const float* emb  = (const float*)d_in[4];
    const float* Wih0 = (const float*)d_in[5];
    const float* Whh0 = (const float*)d_in[6];
    const float* bih0 = (const float*)d_in[7];
    const float* bhh0 = (const float*)d_in[8];
    const float* Wih1 = (const float*)d_in[9];
    const float* Whh1 = (const float*)d_in[10];
    const float* bih1 = (const float*)d_in[11];
    const float* bhh1 = (const float*)d_in[12];
    const float* Wout = (const float*)d_in[13];
    const float* bout = (const float*)d_in[14];
    float* out = (float*)d_out;

    char* w = (char*)d_ws;
    f16* WOUTH = (f16*)w;  w += (size_t)V * 1024 * 2;
    f16* WIH0H = (f16*)w;  w += (size_t)G4 * E * 2;
    f16* WHH0H = (f16*)w;  w += (size_t)G4 * D * 2;
    f16* WIH1H = (f16*)w;  w += (size_t)G4 * D * 2;
    f16* WHH1H = (f16*)w;  w += (size_t)G4 * D * 2;
    f16* YH    = (f16*)w;  w += (size_t)BT * E * 2;
    f16* XH    = (f16*)w;  w += (size_t)BT * 1024 * 2;
    float* PRE0T = (float*)w; w += (size_t)G4 * BT * 4;
    float* S1ALL = (float*)w; w += (size_t)(T + 1) * B * D * 4;
    f16* S0H   = (f16*)w;  w += 2 * 16384 * 2;
    f16* S1H   = (f16*)w;  w += 2 * 16384 * 2;
    float* C0F = (float*)w; w += 16384 * 4;
    float* C1F = (float*)w; w += 16384 * 4;
    float* BIH0 = (float*)w; w += 2048 * 4;
    float* B1   = (float*)w; w += 2048 * 4;

    // weight conversions fp32 -> f16
    convertv<<<4096, 256, 0, stream>>>(Wout, WOUTH, (long)V * 1024);
    convertv<<<256,  256, 0, stream>>>(Wih0, WIH0H, (long)G4 * E);
    convertv<<<512,  256, 0, stream>>>(Whh0, WHH0H, (long)G4 * D);
    convertv<<<512,  256, 0, stream>>>(Wih1, WIH1H, (long)G4 * D);
    convertv<<<512,  256, 0, stream>>>(Whh1, WHH1H, (long)G4 * D);
    bias_prep<<<8, 256, 0, stream>>>(bih0, bhh0, bih1, bhh1, BIH0, B1);
    embed_kernel<<<BT, 256, 0, stream>>>(tar, emb, YH);

    // PRE0T[j][m] = (emb[ids] @ Wih0^T + bih0 + bhh0), M=2048, N=4096, K=256
    gemm_bt<1><<<dim3(32, 16), 256, 0, stream>>>(WIH0H, YH, BIH0, PRE0T, 256);

    // sequential LSTM recurrence (cooperative: 256 blocks x 256 threads)
    void* args[] = { (void*)&WHH0H, (void*)&WIH1H, (void*)&WHH1H, (void*)&PRE0T, (void*)&B1,
                     (void*)&s0, (void*)&c0, (void*)&S1ALL, (void*)&S0H, (void*)&S1H,
                     (void*)&C0F, (void*)&C1F, (void*)&XH };
    hipLaunchCooperativeKernel(reinterpret_cast<void*>(recurrence), dim3(256), dim3(256),
                               args, 0, stream);

    // batched attention over all (b,t)
    attention<<<dim3(16, 32), 256, 0, stream>>>(h, S1ALL, XH);

    // logits: out[b][v][t] = [s1|z] @ Wout^T + bout, M=32000, N=4096, K=1024
    gemm_bt<0><<<dim3(32, 250), 256, 0, stream>>>(WOUTH, XH, bout, out, 1024);
}